// Round 4
// baseline (167.586 us; speedup 1.0000x reference)
//
#include <hip/hip_runtime.h>

// SFM recurrent model via MFMA: B=2048, T=60, D=6, H=64, F=10, O=1.
//
// R1-R11: 78-183 us. R12: transposed GEMM (A=U^T static), NB=8,
//   256 blocks x 512 thr, 73 us. Latency-bound: MfmaUtil 13%, VALU 36%.
// R13 FAILED (128us): launch_bounds(512,4) -> VGPR cap 64 -> spill.
// R14 FAILED (143us): NB=4/512 blocks; 2nd block never co-resident;
//   per-block step time identical -> step is serial-chain bound.
// R15 FAILED (82us): removed 170 P-LDS-reads/wave -> SLOWER. Bank-conf
//   counter BIT-IDENTICAL to R12 -> LDS throughput irrelevant. The
//   regression = shfl folds added to M-phase critical path. Conclusion:
//   wall = 2 barriers + LDS latency + chains, NOT any pipe throughput.
// R16: FUSED M+P, ONE barrier/step. Wave w owns outputs (b=0..7,
//   hc=w*8..w*8+7) and computes ALL 4 gate tiles (mt=w>>1; wave pairs
//   duplicate, MFMA 102->240/block, util headroom) + fre tile (x8
//   redundant). z goes through WAVE-PRIVATE LDS slice: same-wave
//   write->read ordered by lgkmcnt -- NO mid barrier, no cross-wave
//   zt round-trip. h double-buffered in LDS (kills WAR between fast
//   writer / slow reader) -> single end-of-step barrier. All waves
//   run identical streams (no wave-7 laggard). Keeps R15 phasor
//   (no ctab) + 3-deep split MFMA chains. Zero shfl in loop.
//
// Layouts (guide-verified): A[m=lane&15][k=quad*8+j]; B[k=quad*8+j]
// [n=lane&15]; C col=lane&15 (n), row=quad*4+reg (m=row-in-tile).
// B cols 0-7 = h_hi(b0..7), 8-15 = h_lo(b0..7).

#define BB 2048
#define TT 60
#define DD 6
#define HH 64
#define FF 10
#define NB 8      // batches per block

#define XS 968          // xsp per-batch stride in shorts (60*16 + 8 pad)
#define HSK 72          // h row stride in shorts (16 rows: 0-7 hi(b), 8-15 lo(b))
#define HBUF (16 * HSK) // one h buffer (shorts); double-buffered
#define ZP 20           // padded fast-axis stride (floats) for ztp/frep

typedef short bf16x8 __attribute__((ext_vector_type(8)));
typedef float f32x4  __attribute__((ext_vector_type(4)));

__device__ __forceinline__ unsigned short f2bf(float f) {
    union { float f; unsigned u; } v; v.f = f;
    unsigned r = v.u + 0x7fffu + ((v.u >> 16) & 1u);   // RNE
    return (unsigned short)(r >> 16);
}
__device__ __forceinline__ float bf2f(unsigned short b) {
    union { unsigned u; float f; } v; v.u = ((unsigned)b) << 16; return v.f;
}
__device__ __forceinline__ float hsig_f(float v) {
    return __builtin_amdgcn_fmed3f(fmaf(v, 0.16666666666666666f, 0.5f), 0.0f, 1.0f);
}
__device__ __forceinline__ float tanh_f(float x) {
    float xc = fminf(fmaxf(x, -12.0f), 12.0f);
    float e  = __builtin_amdgcn_exp2f(xc * 2.8853900817779268f); // 2*log2(e)
    return (e - 1.0f) * __builtin_amdgcn_rcpf(e + 1.0f);
}
__device__ __forceinline__ float uni(float v) {
    return __int_as_float(__builtin_amdgcn_readfirstlane(__float_as_int(v)));
}
__device__ __forceinline__ void pinv(bf16x8& v) { asm volatile("" : "+v"(v)); }

__global__ __launch_bounds__(512, 1)
void sfm_kernel(
    const float* __restrict__ x,
    const float* __restrict__ W_i,  const float* __restrict__ U_i,  const float* __restrict__ b_i,
    const float* __restrict__ W_ste,const float* __restrict__ U_ste,const float* __restrict__ b_ste,
    const float* __restrict__ W_fre,const float* __restrict__ U_fre,const float* __restrict__ b_fre,
    const float* __restrict__ W_c,  const float* __restrict__ U_c,  const float* __restrict__ b_c,
    const float* __restrict__ W_o,  const float* __restrict__ U_o,  const float* __restrict__ b_o,
    const float* __restrict__ U_a,  const float* __restrict__ b_a,
    const float* __restrict__ W_p,  const float* __restrict__ b_p,
    float* __restrict__ out)
{
    const int tid  = threadIdx.x;
    const int lane = tid & 63;
    const int wave = tid >> 6;      // 0..7
    const int q    = lane >> 4;     // quad 0..3
    const int n16  = lane & 15;
    const int b0   = blockIdx.x * NB;

    __shared__ __align__(16) unsigned short xsp[NB * XS];     // presplit x records
    __shared__ __align__(16) unsigned short hsp2[2 * HBUF];   // double-buffered h
    __shared__ __align__(16) float ztp[8][4 * 16 * ZP];       // per-wave z slices
    __shared__ __align__(16) float frep[8][16 * ZP];          // per-wave fre slices
    __shared__ float red[8][8];

    // ---- init: stage + pre-split x (one (b,s) record per thread) ----
    if (tid < NB * TT) {
        const float* xg = x + (size_t)b0 * (TT * DD) + tid * DD;
        const int b = tid / TT, s = tid - b * TT;
        unsigned short* dst = &xsp[b * XS + s * 16];
        #pragma unroll
        for (int d = 0; d < DD; ++d) {
            const float v = xg[d];
            const unsigned short hb = f2bf(v);
            dst[d]     = hb;
            dst[8 + d] = f2bf(v - bf2f(hb));
        }
        dst[6] = 0x3F80; dst[7] = 0;   // k=70 bias row: 1.0 (hi), k=71: 0
        dst[14] = 0; dst[15] = 0;      // lo-part: k=70,71 = 0
    }
    for (int i = tid; i < 2 * HBUF; i += 512) hsp2[i] = 0;   // h = 0, both buffers

    // ---- A-frags (STATIC): wave computes gates 0..3 of m-tile mt=wave>>1
    //      (t=0..3) + fre tile (t=4). A[m=n16][k=c*32+q*8+j];
    //      k: 0-63 U, 64-69 W, 70 bias. ----
    const int mt = wave >> 1;
    bf16x8 Ah[5][3], Al[5][3];
    #pragma unroll
    for (int t = 0; t < 5; ++t) {
        const bool isfre = (t == 4);
        const int col = mt * 16 + n16;
        const float* Ug = (t == 0) ? U_i : (t == 1) ? U_ste : (t == 2) ? U_c : U_o;
        const float* Wg = (t == 0) ? W_i : (t == 1) ? W_ste : (t == 2) ? W_c : W_o;
        const float* bg = (t == 0) ? b_i : (t == 1) ? b_ste : (t == 2) ? b_c : b_o;
        #pragma unroll
        for (int c = 0; c < 3; ++c) {
            #pragma unroll
            for (int j = 0; j < 8; ++j) {
                const int kv = c * 32 + q * 8 + j;
                float v = 0.0f;
                if (!isfre) {
                    if      (kv < 64)  v = Ug[kv * HH + col];
                    else if (kv < 70)  v = Wg[(kv - 64) * HH + col];
                    else if (kv == 70) v = bg[col];
                } else if (n16 < FF) {
                    if      (kv < 64)  v = U_fre[kv * FF + n16];
                    else if (kv < 70)  v = W_fre[(kv - 64) * FF + n16];
                    else if (kv == 70) v = b_fre[n16];
                }
                const unsigned short hb = f2bf(v);
                Ah[t][c][j] = (short)hb;
                Al[t][c][j] = (short)f2bf(v - bf2f(hb));
            }
            pinv(Ah[t][c]); pinv(Al[t][c]);
        }
    }

    // ---- pointwise consts: thread owns output (b=pb, hcol=pc) ----
    const int pb = tid & 7;
    const int pc = tid >> 3;                            // = wave*8 + (lane>>3)
    const int hcin = ((wave & 1) << 3) | ((lane >> 3) & 7);  // row in m-tile
    const float bav = b_a[pc];
    const float wpv = W_p[pc];
    const float bpv = uni(b_p[0]);
    float uav[FF];
    #pragma unroll
    for (int f = 0; f < FF; ++f) uav[f] = uni(U_a[f]);

    // Rotated-phasor state: T(f,t) = S(f,t) * e^{-i*2pi*f*t/10};
    // T' = fc * R_f * T + cv, R_f = const; A = |T|^2.
    const float CRT[10] = { 1.0f,  0.8090169943749475f,  0.30901699437494745f,
                           -0.30901699437494745f, -0.8090169943749475f, -1.0f,
                           -0.8090169943749475f, -0.30901699437494745f,
                            0.30901699437494745f,  0.8090169943749475f };
    const float SRT[10] = { 0.0f,  0.5877852522924731f,  0.9510565162951535f,
                            0.9510565162951535f,  0.5877852522924731f,  0.0f,
                           -0.5877852522924731f, -0.9510565162951535f,
                           -0.9510565162951535f, -0.5877852522924731f };

    float Tre[FF], Tim[FF];
    #pragma unroll
    for (int f = 0; f < FF; ++f) { Tre[f] = 0.0f; Tim[f] = 0.0f; }
    float hv = 0.0f;

    float* ztw = ztp[wave];
    float* frw = frep[wave];
    const unsigned short* xrp = &xsp[(n16 & 7) * XS + (n16 >> 3) * 8];
    const int hrd  = n16 * HSK;            // B-frag read row
    const int hwr0 = pb * HSK + pc;        // h hi write
    const int hwr1 = (8 + pb) * HSK + pc;  // h lo write

    __syncthreads();

    for (int s = 0; s < TT; ++s) {
        const int hoff = (s & 1) * HBUF;       // read buffer
        // ---- B-frags: h chunks (all lanes), x chunk (q0 rows 64-71) ----
        const unsigned short* hr = &hsp2[hoff + hrd];
        const bf16x8 B0 = *(const bf16x8*)&hr[q * 8];
        const bf16x8 B1 = *(const bf16x8*)&hr[32 + q * 8];
        const bf16x8 xv = *(const bf16x8*)&xrp[s * 16];
        const bf16x8 zf = {0, 0, 0, 0, 0, 0, 0, 0};
        const bf16x8 B2 = (q == 0) ? xv : zf;

        // ---- MFMAs: 5 tiles x two independent 3-chains (Ah | Al) ----
        f32x4 acc[5];
        #pragma unroll
        for (int t = 0; t < 5; ++t) {
            f32x4 aH = {0.0f, 0.0f, 0.0f, 0.0f};
            f32x4 aL = {0.0f, 0.0f, 0.0f, 0.0f};
            aH = __builtin_amdgcn_mfma_f32_16x16x32_bf16(Ah[t][0], B0, aH, 0, 0, 0);
            aL = __builtin_amdgcn_mfma_f32_16x16x32_bf16(Al[t][0], B0, aL, 0, 0, 0);
            aH = __builtin_amdgcn_mfma_f32_16x16x32_bf16(Ah[t][1], B1, aH, 0, 0, 0);
            aL = __builtin_amdgcn_mfma_f32_16x16x32_bf16(Al[t][1], B1, aL, 0, 0, 0);
            aH = __builtin_amdgcn_mfma_f32_16x16x32_bf16(Ah[t][2], B2, aH, 0, 0, 0);
            aL = __builtin_amdgcn_mfma_f32_16x16x32_bf16(Al[t][2], B2, aL, 0, 0, 0);
            acc[t] = aH + aL;
        }

        // ---- write z to WAVE-PRIVATE slice (no barrier needed):
        //      slice layout [tile][colpart n16][row], b128 over rows ----
        #pragma unroll
        for (int t = 0; t < 4; ++t)
            *(f32x4*)&ztw[(t * 16 + n16) * ZP + q * 4] = acc[t];
        *(f32x4*)&frw[n16 * ZP + q * 4] = acc[4];
        // (compiler inserts lgkmcnt drain before the dependent reads below)

        // ---- P: all 512 threads, own (b=pb, hc=pc); read own wave slice ----
        const float zi = ztw[(0 * 16 + pb) * ZP + hcin] + ztw[(0 * 16 + pb + 8) * ZP + hcin];
        const float zs = ztw[(1 * 16 + pb) * ZP + hcin] + ztw[(1 * 16 + pb + 8) * ZP + hcin];
        const float zc = ztw[(2 * 16 + pb) * ZP + hcin] + ztw[(2 * 16 + pb + 8) * ZP + hcin];
        const float zo = ztw[(3 * 16 + pb) * ZP + hcin] + ztw[(3 * 16 + pb + 8) * ZP + hcin];

        const float4 fh0 = *(const float4*)&frw[pb * ZP];
        const float4 fl0 = *(const float4*)&frw[(pb + 8) * ZP];
        const float4 fh1 = *(const float4*)&frw[pb * ZP + 4];
        const float4 fl1 = *(const float4*)&frw[(pb + 8) * ZP + 4];
        const float2 fh2 = *(const float2*)&frw[pb * ZP + 8];
        const float2 fl2 = *(const float2*)&frw[(pb + 8) * ZP + 8];
        float fr[FF];
        fr[0] = hsig_f(fh0.x + fl0.x); fr[1] = hsig_f(fh0.y + fl0.y);
        fr[2] = hsig_f(fh0.z + fl0.z); fr[3] = hsig_f(fh0.w + fl0.w);
        fr[4] = hsig_f(fh1.x + fl1.x); fr[5] = hsig_f(fh1.y + fl1.y);
        fr[6] = hsig_f(fh1.z + fl1.z); fr[7] = hsig_f(fh1.w + fl1.w);
        fr[8] = hsig_f(fh2.x + fl2.x); fr[9] = hsig_f(fh2.y + fl2.y);

        const float iv  = hsig_f(zi);
        const float stv = hsig_f(zs);
        const float ov  = hsig_f(zo);
        const float cv  = iv * tanh_f(zc);

        float aacc0 = bav, aacc1 = 0.0f;
        #pragma unroll
        for (int f = 0; f < FF; ++f) {
            const float fc = stv * fr[f];
            const float tre = fmaf(SRT[f], Tim[f],  CRT[f] * Tre[f]);
            const float tim = fmaf(CRT[f], Tim[f], -SRT[f] * Tre[f]);
            Tre[f] = fmaf(fc, tre, cv);
            Tim[f] = fc * tim;
            const float A = fmaf(Tim[f], Tim[f], Tre[f] * Tre[f]);
            if (f & 1) aacc1 = fmaf(A, uav[f], aacc1);
            else       aacc0 = fmaf(A, uav[f], aacc0);
        }
        hv = ov * tanh_f(aacc0 + aacc1);

        // split h -> bf16 hi/lo rows into the OTHER buffer (WAR-safe)
        {
            const int woff = HBUF - hoff;
            const unsigned short hb = f2bf(hv);
            hsp2[woff + hwr0] = hb;
            hsp2[woff + hwr1] = f2bf(hv - bf2f(hb));
        }
        __syncthreads();   // the ONLY barrier per step
    }

    // ---- output: out[b] = sum_hc h*W_p + b_p ----
    // lane bits: pb = lane&7, hc-in-wave = lane>>3 -> fold bits 3..5
    float val = hv * wpv;
    val += __shfl_xor(val, 8, 64);
    val += __shfl_xor(val, 16, 64);
    val += __shfl_xor(val, 32, 64);
    if (lane < 8) red[wave][lane] = val;
    __syncthreads();
    if (tid < NB) {
        float acc = bpv;
        #pragma unroll
        for (int w = 0; w < 8; ++w) acc += red[w][tid];
        out[b0 + tid] = acc;
    }
}

extern "C" void kernel_launch(void* const* d_in, const int* in_sizes, int n_in,
                              void* d_out, int out_size, void* d_ws, size_t ws_size,
                              hipStream_t stream) {
    (void)in_sizes; (void)n_in; (void)d_ws; (void)ws_size; (void)out_size;
    const float* x     = (const float*)d_in[0];
    const float* W_i   = (const float*)d_in[1];
    const float* U_i   = (const float*)d_in[2];
    const float* b_i   = (const float*)d_in[3];
    const float* W_ste = (const float*)d_in[4];
    const float* U_ste = (const float*)d_in[5];
    const float* b_ste = (const float*)d_in[6];
    const float* W_fre = (const float*)d_in[7];
    const float* U_fre = (const float*)d_in[8];
    const float* b_fre = (const float*)d_in[9];
    const float* W_c   = (const float*)d_in[10];
    const float* U_c   = (const float*)d_in[11];
    const float* b_c   = (const float*)d_in[12];
    const float* W_o   = (const float*)d_in[13];
    const float* U_o   = (const float*)d_in[14];
    const float* b_o   = (const float*)d_in[15];
    const float* U_a   = (const float*)d_in[16];
    const float* b_a   = (const float*)d_in[17];
    const float* W_p   = (const float*)d_in[18];
    const float* b_p   = (const float*)d_in[19];

    sfm_kernel<<<BB / NB, 512, 0, stream>>>(
        x, W_i, U_i, b_i, W_ste, U_ste, b_ste, W_fre, U_fre, b_fre,
        W_c, U_c, b_c, W_o, U_o, b_o, U_a, b_a, W_p, b_p, (float*)d_out);
}

// Round 5
// 164.688 us; speedup vs baseline: 1.0176x; 1.0176x over previous
//
#include <hip/hip_runtime.h>

// SFM recurrent model via MFMA: B=2048, T=60, D=6, H=64, F=10, O=1.
//
// R12 BEST (73.7us): transposed GEMM (A=U^T static), NB=8, 256x512,
//   2 barriers/step, all waves do M then all do P. MfmaUtil 13, VALU 36.
// R13/R14: multi-block-residency axis dead (spill / no co-residency).
//   R14 lesson: halving P threads doesn't change wall -> P issue not bound.
// R15 (82us): -170 P LDS reads -> SLOWER; bank-conflict ctr bit-identical
//   -> LDS throughput irrelevant; shfl on M path costs ~30cy each.
// R16 (93us): fused M+P, 1 barrier/step, MFMA/SIMD 25->60. Wall grew
//   ~1:1 with added matrix-pipe time; barrier removal saved ~nothing.
//   LESSON: MFMA pipe time adds to wall because of PHASE LOCKSTEP --
//   M-phase (matrix busy, VALU idle) and P-phase (VALU busy, matrix
//   idle) never overlap.
// R17: TWO-GROUP PIPELINE. Groups of 4 batches (R14's proven 4-batch
//   col mapping). Interval 2s: M(G0,s) || P(G1,s-1); 2s+1: M(G1,s) ||
//   P(G0,s). Wave-specialized: waves 0-3 = M (wave w owns 4 gates of
//   m-tile w, 24 MFMA; wave 0 adds fre), waves 4-7 = P (4b x 64col).
//   Disjoint static LDS per group (ztA/ztB...) -> compiler sees no
//   alias; M and P halves have zero data dependence inside an interval
//   -> matrix pipe and VALU finally run concurrently. Same 2 barriers
//   per s as R12. Per-batch MFMA doubles (headroom: 13% util).
//
// Layouts (guide-verified): A[m=lane&15][k=quad*8+j]; B[k=quad*8+j]
// [n=lane&15]; C col=lane&15 (n), row=quad*4+reg. Group B cols:
// 0-3 h_hi(b0..3), 8-11 h_lo; cols 4-7/12-15 garbage-but-finite
// (zero h rows / duplicate x rows), outputs ignored (R14-proven).

#define BB 2048
#define TT 60
#define DD 6
#define HH 64
#define FF 10
#define NB 8      // batches per block (2 groups of 4)

#define XS 968    // xsp per-batch stride in shorts (60*16 + 8 pad)
#define HSK 72    // h row stride in shorts (16 rows: 0-3 hi(b), 8-11 lo(b))
#define ZC 68     // zt hcol stride in floats (pad 64->68)

typedef short bf16x8 __attribute__((ext_vector_type(8)));
typedef float f32x4  __attribute__((ext_vector_type(4)));

__device__ __forceinline__ unsigned short f2bf(float f) {
    union { float f; unsigned u; } v; v.f = f;
    unsigned r = v.u + 0x7fffu + ((v.u >> 16) & 1u);   // RNE
    return (unsigned short)(r >> 16);
}
__device__ __forceinline__ float bf2f(unsigned short b) {
    union { unsigned u; float f; } v; v.u = ((unsigned)b) << 16; return v.f;
}
__device__ __forceinline__ float hsig_f(float v) {
    return __builtin_amdgcn_fmed3f(fmaf(v, 0.16666666666666666f, 0.5f), 0.0f, 1.0f);
}
__device__ __forceinline__ float tanh_f(float x) {
    float xc = fminf(fmaxf(x, -12.0f), 12.0f);
    float e  = __builtin_amdgcn_exp2f(xc * 2.8853900817779268f); // 2*log2(e)
    return (e - 1.0f) * __builtin_amdgcn_rcpf(e + 1.0f);
}
__device__ __forceinline__ float uni(float v) {
    return __int_as_float(__builtin_amdgcn_readfirstlane(__float_as_int(v)));
}
__device__ __forceinline__ void pinv(bf16x8& v) { asm volatile("" : "+v"(v)); }

// ---- M half-interval: GEMV for one group (waves 0-3; wave 0 adds fre) ----
#define MBODY(HSPN, XRPN, ZTN, FBN, SS)                                       \
  do {                                                                        \
    const unsigned short* hr_ = &HSPN[n16 * HSK];                             \
    const bf16x8 B0 = *(const bf16x8*)&hr_[q * 8];                            \
    const bf16x8 B1 = *(const bf16x8*)&hr_[32 + q * 8];                       \
    const bf16x8 xv = *(const bf16x8*)&XRPN[(SS) * 16];                       \
    const bf16x8 zf8 = {0, 0, 0, 0, 0, 0, 0, 0};                              \
    const bf16x8 B2 = (q == 0) ? xv : zf8;                                    \
    _Pragma("unroll")                                                         \
    for (int t = 0; t < 4; ++t) {                                             \
      f32x4 a = {0.0f, 0.0f, 0.0f, 0.0f};                                     \
      a = __builtin_amdgcn_mfma_f32_16x16x32_bf16(Ah[t][0], B0, a, 0, 0, 0);  \
      a = __builtin_amdgcn_mfma_f32_16x16x32_bf16(Al[t][0], B0, a, 0, 0, 0);  \
      a = __builtin_amdgcn_mfma_f32_16x16x32_bf16(Ah[t][1], B1, a, 0, 0, 0);  \
      a = __builtin_amdgcn_mfma_f32_16x16x32_bf16(Al[t][1], B1, a, 0, 0, 0);  \
      a = __builtin_amdgcn_mfma_f32_16x16x32_bf16(Ah[t][2], B2, a, 0, 0, 0);  \
      a = __builtin_amdgcn_mfma_f32_16x16x32_bf16(Al[t][2], B2, a, 0, 0, 0);  \
      *(f32x4*)&ZTN[(t * 16 + n16) * ZC + wave * 16 + q * 4] = a;             \
    }                                                                         \
    if (wave == 0) {                                                          \
      f32x4 a = {0.0f, 0.0f, 0.0f, 0.0f};                                     \
      a = __builtin_amdgcn_mfma_f32_16x16x32_bf16(Ah[4][0], B0, a, 0, 0, 0);  \
      a = __builtin_amdgcn_mfma_f32_16x16x32_bf16(Al[4][0], B0, a, 0, 0, 0);  \
      a = __builtin_amdgcn_mfma_f32_16x16x32_bf16(Ah[4][1], B1, a, 0, 0, 0);  \
      a = __builtin_amdgcn_mfma_f32_16x16x32_bf16(Al[4][1], B1, a, 0, 0, 0);  \
      a = __builtin_amdgcn_mfma_f32_16x16x32_bf16(Ah[4][2], B2, a, 0, 0, 0);  \
      a = __builtin_amdgcn_mfma_f32_16x16x32_bf16(Al[4][2], B2, a, 0, 0, 0);  \
      f32x4 af;                                                               \
      _Pragma("unroll")                                                       \
      for (int r = 0; r < 4; ++r)                                             \
        af[r] = a[r] + __shfl_xor(a[r], 8, 64);                               \
      if (n16 < 4) {                                                          \
        _Pragma("unroll")                                                     \
        for (int r = 0; r < 4; ++r) {                                         \
          const int f_ = q * 4 + r;                                           \
          if (f_ < FF) FBN[n16 * 12 + f_] = af[r];                            \
        }                                                                     \
      }                                                                       \
    }                                                                         \
  } while (0)

// ---- P half-interval: pointwise for one group (waves 4-7) ----
#define PBODY(ZTN, FBN, HSPN, SRE, SIM, HV, MV)                               \
  do {                                                                        \
    const float zi  = ZTN[(0*16+pb)*ZC+pc] + ZTN[(0*16+pb+8)*ZC+pc];          \
    const float zs  = ZTN[(1*16+pb)*ZC+pc] + ZTN[(1*16+pb+8)*ZC+pc];          \
    const float zc_ = ZTN[(2*16+pb)*ZC+pc] + ZTN[(2*16+pb+8)*ZC+pc];          \
    const float zo  = ZTN[(3*16+pb)*ZC+pc] + ZTN[(3*16+pb+8)*ZC+pc];          \
    const float4 fb0 = *(const float4*)&FBN[pb * 12];                         \
    const float4 fb1 = *(const float4*)&FBN[pb * 12 + 4];                     \
    const float2 fb2 = *(const float2*)&FBN[pb * 12 + 8];                     \
    const float* tp_ = &ctab[(MV) * 20];                                      \
    const float4 t0 = *(const float4*)&tp_[0];                                \
    const float4 t1 = *(const float4*)&tp_[4];                                \
    const float4 t2 = *(const float4*)&tp_[8];                                \
    const float4 t3 = *(const float4*)&tp_[12];                               \
    const float4 t4 = *(const float4*)&tp_[16];                               \
    const float tvc[FF] = { t0.x, t0.z, t1.x, t1.z, t2.x,                     \
                            t2.z, t3.x, t3.z, t4.x, t4.z };                   \
    const float tvs[FF] = { t0.y, t0.w, t1.y, t1.w, t2.y,                     \
                            t2.w, t3.y, t3.w, t4.y, t4.w };                   \
    float fr_[FF];                                                            \
    fr_[0] = hsig_f(fb0.x); fr_[1] = hsig_f(fb0.y);                           \
    fr_[2] = hsig_f(fb0.z); fr_[3] = hsig_f(fb0.w);                           \
    fr_[4] = hsig_f(fb1.x); fr_[5] = hsig_f(fb1.y);                           \
    fr_[6] = hsig_f(fb1.z); fr_[7] = hsig_f(fb1.w);                           \
    fr_[8] = hsig_f(fb2.x); fr_[9] = hsig_f(fb2.y);                           \
    const float iv  = hsig_f(zi);                                             \
    const float stv = hsig_f(zs);                                             \
    const float ov  = hsig_f(zo);                                             \
    const float cv  = iv * tanh_f(zc_);                                       \
    float aacc0 = bav, aacc1 = 0.0f;                                          \
    _Pragma("unroll")                                                         \
    for (int f = 0; f < FF; ++f) {                                            \
      const float fc = stv * fr_[f];                                          \
      SRE[f] = fmaf(fc, SRE[f], cv * tvc[f]);                                 \
      SIM[f] = fmaf(fc, SIM[f], cv * tvs[f]);                                 \
      const float A_ = fmaf(SIM[f], SIM[f], SRE[f] * SRE[f]);                 \
      if (f & 1) aacc1 = fmaf(A_, uav[f], aacc1);                             \
      else       aacc0 = fmaf(A_, uav[f], aacc0);                             \
    }                                                                         \
    HV = ov * tanh_f(aacc0 + aacc1);                                          \
    const unsigned short hb_ = f2bf(HV);                                      \
    HSPN[pb * HSK + pc]       = hb_;                                          \
    HSPN[(8 + pb) * HSK + pc] = f2bf(HV - bf2f(hb_));                         \
  } while (0)

__global__ __launch_bounds__(512, 1)
void sfm_kernel(
    const float* __restrict__ x,
    const float* __restrict__ W_i,  const float* __restrict__ U_i,  const float* __restrict__ b_i,
    const float* __restrict__ W_ste,const float* __restrict__ U_ste,const float* __restrict__ b_ste,
    const float* __restrict__ W_fre,const float* __restrict__ U_fre,const float* __restrict__ b_fre,
    const float* __restrict__ W_c,  const float* __restrict__ U_c,  const float* __restrict__ b_c,
    const float* __restrict__ W_o,  const float* __restrict__ U_o,  const float* __restrict__ b_o,
    const float* __restrict__ U_a,  const float* __restrict__ b_a,
    const float* __restrict__ W_p,  const float* __restrict__ b_p,
    float* __restrict__ out)
{
    const int tid  = threadIdx.x;
    const int lane = tid & 63;
    const int wave = tid >> 6;      // 0..7
    const int q    = lane >> 4;     // quad 0..3
    const int n16  = lane & 15;
    const int b0   = blockIdx.x * NB;

    __shared__ __align__(16) unsigned short xsp[NB * XS];
    __shared__ __align__(16) unsigned short hspA[16 * HSK];
    __shared__ __align__(16) unsigned short hspB[16 * HSK];
    __shared__ __align__(16) float ztA[4 * 16 * ZC];
    __shared__ __align__(16) float ztB[4 * 16 * ZC];
    __shared__ __align__(16) float fbA[4 * 12];
    __shared__ __align__(16) float fbB[4 * 12];
    __shared__ __align__(16) float ctab[10 * 10 * 2];
    __shared__ float cstabB[10 * 2];
    __shared__ float red[2][4][4];

    // ---- init: stage + pre-split x (one (b,s) record per thread) ----
    if (tid < NB * TT) {
        const float* xg = x + (size_t)b0 * (TT * DD) + tid * DD;
        const int b = tid / TT, s = tid - b * TT;
        unsigned short* dst = &xsp[b * XS + s * 16];
        #pragma unroll
        for (int d = 0; d < DD; ++d) {
            const float v = xg[d];
            const unsigned short hb = f2bf(v);
            dst[d]     = hb;
            dst[8 + d] = f2bf(v - bf2f(hb));
        }
        dst[6] = 0x3F80; dst[7] = 0;   // k=70 bias row: 1.0 (hi), k=71: 0
        dst[14] = 0; dst[15] = 0;
    }
    if (tid < 10) {
        const float CTc[10] = { 1.0f,  0.8090169943749475f,  0.30901699437494745f,
                               -0.30901699437494745f, -0.8090169943749475f, -1.0f,
                               -0.8090169943749475f, -0.30901699437494745f,
                                0.30901699437494745f,  0.8090169943749475f };
        const float STc[10] = { 0.0f,  0.5877852522924731f,  0.9510565162951535f,
                                0.9510565162951535f,  0.5877852522924731f,  0.0f,
                               -0.5877852522924731f, -0.9510565162951535f,
                               -0.9510565162951535f, -0.5877852522924731f };
        float cc = 0.0f, ss = 0.0f;
        #pragma unroll
        for (int j = 0; j < 10; ++j) if (tid == j) { cc = CTc[j]; ss = STc[j]; }
        cstabB[tid * 2] = cc; cstabB[tid * 2 + 1] = ss;
    }
    for (int i = tid; i < 16 * HSK; i += 512) { hspA[i] = 0; hspB[i] = 0; }
    __syncthreads();
    if (tid < 100) {
        const int mm = tid / 10, ff = tid - mm * 10;
        const int idx = (ff * mm) % 10;
        ctab[tid * 2]     = cstabB[idx * 2];
        ctab[tid * 2 + 1] = cstabB[idx * 2 + 1];
    }

    // ---- A-frags (STATIC): wave w (0-3) owns all 4 gates of m-tile w;
    //      wave 0 adds fre (t=4). A[m=n16][k=c*32+q*8+j]. ----
    bf16x8 Ah[5][3], Al[5][3];
    if (wave < 4) {
        const int col = wave * 16 + n16;
        #pragma unroll
        for (int t = 0; t < 4; ++t) {
            const float* Ug = (t == 0) ? U_i : (t == 1) ? U_ste : (t == 2) ? U_c : U_o;
            const float* Wg = (t == 0) ? W_i : (t == 1) ? W_ste : (t == 2) ? W_c : W_o;
            const float* bg = (t == 0) ? b_i : (t == 1) ? b_ste : (t == 2) ? b_c : b_o;
            #pragma unroll
            for (int c = 0; c < 3; ++c) {
                #pragma unroll
                for (int j = 0; j < 8; ++j) {
                    const int kv = c * 32 + q * 8 + j;
                    float v = 0.0f;
                    if      (kv < 64)  v = Ug[kv * HH + col];
                    else if (kv < 70)  v = Wg[(kv - 64) * HH + col];
                    else if (kv == 70) v = bg[col];
                    const unsigned short hb = f2bf(v);
                    Ah[t][c][j] = (short)hb;
                    Al[t][c][j] = (short)f2bf(v - bf2f(hb));
                }
                pinv(Ah[t][c]); pinv(Al[t][c]);
            }
        }
    }
    if (wave == 0) {   // fre tile
        #pragma unroll
        for (int c = 0; c < 3; ++c) {
            #pragma unroll
            for (int j = 0; j < 8; ++j) {
                const int kv = c * 32 + q * 8 + j;
                float v = 0.0f;
                if (n16 < FF) {
                    if      (kv < 64)  v = U_fre[kv * FF + n16];
                    else if (kv < 70)  v = W_fre[(kv - 64) * FF + n16];
                    else if (kv == 70) v = b_fre[n16];
                }
                const unsigned short hb = f2bf(v);
                Ah[4][c][j] = (short)hb;
                Al[4][c][j] = (short)f2bf(v - bf2f(hb));
            }
            pinv(Ah[4][c]); pinv(Al[4][c]);
        }
    }

    // ---- P consts (P-waves 4-7; loads valid for all threads) ----
    const int pb = tid & 3;
    const int pc = (tid & 255) >> 2;    // 0..63
    const float bav = b_a[pc];
    const float wpv = W_p[pc];
    const float bpv = uni(b_p[0]);
    float uav[FF];
    #pragma unroll
    for (int f = 0; f < FF; ++f) uav[f] = uni(U_a[f]);

    float SreA[FF], SimA[FF], SreB[FF], SimB[FF];
    #pragma unroll
    for (int f = 0; f < FF; ++f) {
        SreA[f] = 0.0f; SimA[f] = 0.0f;
        SreB[f] = 0.0f; SimB[f] = 0.0f;
    }
    float hvA = 0.0f, hvB = 0.0f;

    // x record pointers per group (B cols: batch n16&3, part n16>>3)
    const unsigned short* xrpA = &xsp[(0 + (n16 & 3)) * XS + (n16 >> 3) * 8];
    const unsigned short* xrpB = &xsp[(4 + (n16 & 3)) * XS + (n16 >> 3) * 8];

    __syncthreads();

    int mE = 0, mO = 1;
    for (int s = 0; s < TT; ++s) {
        // ---- even interval: M(G0, s) || P(G1, s-1) ----
        if (wave < 4) {
            MBODY(hspA, xrpA, ztA, fbA, s);
        } else if (s > 0) {
            PBODY(ztB, fbB, hspB, SreB, SimB, hvB, mE);
        }
        __syncthreads();
        // ---- odd interval: M(G1, s) || P(G0, s) ----
        if (wave < 4) {
            MBODY(hspB, xrpB, ztB, fbB, s);
        } else {
            PBODY(ztA, fbA, hspA, SreA, SimA, hvA, mO);
        }
        __syncthreads();
        mE = mO; mO = (mO + 1 == 10) ? 0 : mO + 1;
    }
    // ---- tail: P(G1, 59) ----
    if (wave >= 4) {
        PBODY(ztB, fbB, hspB, SreB, SimB, hvB, mE);
    }

    // ---- output: out[b] = sum_hc h*W_p + b_p ----
    // P lane bits: pb = lane&3, pc-in-wave = lane>>2 -> fold bits 2..5
    float va = hvA * wpv;
    float vb = hvB * wpv;
    va += __shfl_xor(va, 4, 64);  vb += __shfl_xor(vb, 4, 64);
    va += __shfl_xor(va, 8, 64);  vb += __shfl_xor(vb, 8, 64);
    va += __shfl_xor(va, 16, 64); vb += __shfl_xor(vb, 16, 64);
    va += __shfl_xor(va, 32, 64); vb += __shfl_xor(vb, 32, 64);
    if (wave >= 4 && lane < 4) {
        red[0][wave - 4][lane] = va;
        red[1][wave - 4][lane] = vb;
    }
    __syncthreads();
    if (tid < 8) {
        const int g = tid >> 2, b = tid & 3;
        float acc = bpv;
        #pragma unroll
        for (int w = 0; w < 4; ++w) acc += red[g][w][b];
        out[b0 + g * 4 + b] = acc;
    }
}

extern "C" void kernel_launch(void* const* d_in, const int* in_sizes, int n_in,
                              void* d_out, int out_size, void* d_ws, size_t ws_size,
                              hipStream_t stream) {
    (void)in_sizes; (void)n_in; (void)d_ws; (void)ws_size; (void)out_size;
    const float* x     = (const float*)d_in[0];
    const float* W_i   = (const float*)d_in[1];
    const float* U_i   = (const float*)d_in[2];
    const float* b_i   = (const float*)d_in[3];
    const float* W_ste = (const float*)d_in[4];
    const float* U_ste = (const float*)d_in[5];
    const float* b_ste = (const float*)d_in[6];
    const float* W_fre = (const float*)d_in[7];
    const float* U_fre = (const float*)d_in[8];
    const float* b_fre = (const float*)d_in[9];
    const float* W_c   = (const float*)d_in[10];
    const float* U_c   = (const float*)d_in[11];
    const float* b_c   = (const float*)d_in[12];
    const float* W_o   = (const float*)d_in[13];
    const float* U_o   = (const float*)d_in[14];
    const float* b_o   = (const float*)d_in[15];
    const float* U_a   = (const float*)d_in[16];
    const float* b_a   = (const float*)d_in[17];
    const float* W_p   = (const float*)d_in[18];
    const float* b_p   = (const float*)d_in[19];

    sfm_kernel<<<BB / NB, 512, 0, stream>>>(
        x, W_i, U_i, b_i, W_ste, U_ste, b_ste, W_fre, U_fre, b_fre,
        W_c, U_c, b_c, W_o, U_o, b_o, U_a, b_a, W_p, b_p, (float*)d_out);
}

// Round 6
// 158.987 us; speedup vs baseline: 1.0541x; 1.0359x over previous
//
#include <hip/hip_runtime.h>

// SFM recurrent model via MFMA: B=2048, T=60, D=6, H=64, F=10, O=1.
//
// R12 BEST (73.7us): transposed GEMM (A=U^T static), NB=8, 256x512,
//   2 barriers/step. Latency/serialization-bound: MfmaUtil 13, VALU 36.
// R13/R14: multi-block axis dead (spill / no co-residency).
// R15 (82us): phasor+fb-vec+chain-split GOOD, but M-phase shfl folds
//   (8 ds-swizzle/wave pre-barrier = LDS-pipe ops on critical path)
//   regressed. Bank-conflict ctr identical -> pipe total conserved.
// R16 (93us): fuse M+P, 1 barrier, 2x MFMA -> wall +~1:1 w/ pipe time.
// R17 (87.6us): M||P wave-specialized pipeline, 2x per-batch MFMA.
//   Overlap real (beat R16) but duplication tax > overlap gain.
//   LEDGER: 2 cross-wave handoffs/step => 2 barriers irreducible
//   without duplication; duplication never pays. Keep R12 skeleton,
//   shave the P-phase LDS convoy (8 waves x 21 ops -> x 11 ops).
// R18 = R12 + isolated R15 goods, minus its mistake:
//   (a) phasor: T(f,t)=S*e^{-i*2pi*f*t/10}; T' = fc*R_f*T + cv with
//       R_f compile-time const; A=|T|^2. Kills 10 ctab b64 reads
//       per thread per step + the m counter. (verified in R15)
//   (b) fb reads vectorized: 10 scalar -> f4+f4+f2.
//   (c) MFMA 6-chain -> two independent 3-chains (aH|aL) + add.
//   (d) x-record read prefetched into regs during previous P phase
//       (off the post-barrier M critical path).
//   zt stays R12 [4][16][ZC], 8 b32 P-reads, NO new M-phase shfl.
//
// Layouts (guide-verified): A[m=lane&15][k=quad*8+j]; B[k=quad*8+j]
// [n=lane&15]; C col=lane&15 (n), row=quad*4+reg (m=hcol-in-tile).
// B cols 0-7 = h_hi(b0..7), 8-15 = h_lo(b0..7).

#define BB 2048
#define TT 60
#define DD 6
#define HH 64
#define FF 10
#define NB 8      // batches per block

#define XS 968    // xsp per-batch stride in shorts (60*16 + 8 pad)
#define HSK 72    // hsp2 row stride in shorts (16 rows: 0-7 hi(b), 8-15 lo(b))
#define ZC 68     // zt hcol stride in floats (pad 64->68: banks spread)

typedef short bf16x8 __attribute__((ext_vector_type(8)));
typedef float f32x4  __attribute__((ext_vector_type(4)));

__device__ __forceinline__ unsigned short f2bf(float f) {
    union { float f; unsigned u; } v; v.f = f;
    unsigned r = v.u + 0x7fffu + ((v.u >> 16) & 1u);   // RNE
    return (unsigned short)(r >> 16);
}
__device__ __forceinline__ float bf2f(unsigned short b) {
    union { unsigned u; float f; } v; v.u = ((unsigned)b) << 16; return v.f;
}
__device__ __forceinline__ float hsig_f(float v) {
    return __builtin_amdgcn_fmed3f(fmaf(v, 0.16666666666666666f, 0.5f), 0.0f, 1.0f);
}
__device__ __forceinline__ float tanh_f(float x) {
    float xc = fminf(fmaxf(x, -12.0f), 12.0f);
    float e  = __builtin_amdgcn_exp2f(xc * 2.8853900817779268f); // 2*log2(e)
    return (e - 1.0f) * __builtin_amdgcn_rcpf(e + 1.0f);
}
__device__ __forceinline__ float uni(float v) {
    return __int_as_float(__builtin_amdgcn_readfirstlane(__float_as_int(v)));
}
__device__ __forceinline__ void pinv(bf16x8& v) { asm volatile("" : "+v"(v)); }

__global__ __launch_bounds__(512, 1)
void sfm_kernel(
    const float* __restrict__ x,
    const float* __restrict__ W_i,  const float* __restrict__ U_i,  const float* __restrict__ b_i,
    const float* __restrict__ W_ste,const float* __restrict__ U_ste,const float* __restrict__ b_ste,
    const float* __restrict__ W_fre,const float* __restrict__ U_fre,const float* __restrict__ b_fre,
    const float* __restrict__ W_c,  const float* __restrict__ U_c,  const float* __restrict__ b_c,
    const float* __restrict__ W_o,  const float* __restrict__ U_o,  const float* __restrict__ b_o,
    const float* __restrict__ U_a,  const float* __restrict__ b_a,
    const float* __restrict__ W_p,  const float* __restrict__ b_p,
    float* __restrict__ out)
{
    const int tid  = threadIdx.x;
    const int lane = tid & 63;
    const int wave = tid >> 6;      // 0..7
    const int q    = lane >> 4;     // quad 0..3
    const int n16  = lane & 15;
    const int b0   = blockIdx.x * NB;

    __shared__ __align__(16) unsigned short xsp[NB * XS];   // presplit x records
    __shared__ __align__(16) unsigned short hsp2[16 * HSK]; // rows 0-7 hhi(b), 8-15 hlo(b)
    __shared__ __align__(16) float zt[4 * 16 * ZC];         // [g][col(part,b)][hcol]
    __shared__ __align__(16) float fb[NB * 12];             // zfre[b][f], parts folded
    __shared__ float red[8][8];

    // ---- init: stage + pre-split x (one (b,s) record per thread) ----
    if (tid < NB * TT) {
        const float* xg = x + (size_t)b0 * (TT * DD) + tid * DD;
        const int b = tid / TT, s = tid - b * TT;
        unsigned short* dst = &xsp[b * XS + s * 16];
        #pragma unroll
        for (int d = 0; d < DD; ++d) {
            const float v = xg[d];
            const unsigned short hb = f2bf(v);
            dst[d]     = hb;
            dst[8 + d] = f2bf(v - bf2f(hb));
        }
        dst[6] = 0x3F80; dst[7] = 0;   // k=70 bias row: 1.0 (hi), k=71: 0
        dst[14] = 0; dst[15] = 0;      // lo-part: k=70,71 = 0
    }
    for (int i = tid; i < 16 * HSK; i += 512) hsp2[i] = 0;   // h = 0 (hi & lo)

    // ---- A-frags (STATIC, U^T orientation): wave w owns gate tiles
    //      gt=2w, 2w+1 (g=gt>>2, mt=gt&3); wave 7 adds fre tile (t=2).
    //      A[m=n16][k = c*32 + q*8 + j]; k: 0-63 U, 64-69 W, 70 bias. ----
    const int NTILE = (wave == 7) ? 3 : 2;
    bf16x8 Ah[3][3], Al[3][3];
    #pragma unroll
    for (int t = 0; t < 3; ++t) {
        if (t >= NTILE) continue;
        const bool isfre = (wave == 7 && t == 2);
        const int gt = 2 * wave + t;
        const int g  = gt >> 2, mt = gt & 3;
        const int col = mt * 16 + n16;
        const float* Ug = (g == 0) ? U_i : (g == 1) ? U_ste : (g == 2) ? U_c : U_o;
        const float* Wg = (g == 0) ? W_i : (g == 1) ? W_ste : (g == 2) ? W_c : W_o;
        const float* bg = (g == 0) ? b_i : (g == 1) ? b_ste : (g == 2) ? b_c : b_o;
        #pragma unroll
        for (int c = 0; c < 3; ++c) {
            #pragma unroll
            for (int j = 0; j < 8; ++j) {
                const int kv = c * 32 + q * 8 + j;
                float v = 0.0f;
                if (!isfre) {
                    if      (kv < 64)  v = Ug[kv * HH + col];
                    else if (kv < 70)  v = Wg[(kv - 64) * HH + col];
                    else if (kv == 70) v = bg[col];
                } else if (n16 < FF) {
                    if      (kv < 64)  v = U_fre[kv * FF + n16];
                    else if (kv < 70)  v = W_fre[(kv - 64) * FF + n16];
                    else if (kv == 70) v = b_fre[n16];
                }
                const unsigned short hb = f2bf(v);
                Ah[t][c][j] = (short)hb;
                Al[t][c][j] = (short)f2bf(v - bf2f(hb));
            }
            pinv(Ah[t][c]); pinv(Al[t][c]);
        }
    }

    // ---- pointwise consts: pb = tid&7, pc = tid>>3 (0..63) ----
    const int pb = tid & 7;
    const int pc = tid >> 3;
    const float bav = b_a[pc];
    const float wpv = W_p[pc];
    const float bpv = uni(b_p[0]);
    float uav[FF];
    #pragma unroll
    for (int f = 0; f < FF; ++f) uav[f] = uni(U_a[f]);

    // Rotated-phasor state (R15-verified): T(f,t) = S(f,t)*e^{-i*2pi*f*t/10};
    // T' = fc * R_f * T + cv, R_f = e^{-i*2pi*f/10} const; A = |T|^2.
    const float CRT[10] = { 1.0f,  0.8090169943749475f,  0.30901699437494745f,
                           -0.30901699437494745f, -0.8090169943749475f, -1.0f,
                           -0.8090169943749475f, -0.30901699437494745f,
                            0.30901699437494745f,  0.8090169943749475f };
    const float SRT[10] = { 0.0f,  0.5877852522924731f,  0.9510565162951535f,
                            0.9510565162951535f,  0.5877852522924731f,  0.0f,
                           -0.5877852522924731f, -0.9510565162951535f,
                           -0.9510565162951535f, -0.5877852522924731f };

    float Tre[FF], Tim[FF];
    #pragma unroll
    for (int f = 0; f < FF; ++f) { Tre[f] = 0.0f; Tim[f] = 0.0f; }
    float hv = 0.0f;

    // B-frag addresses (dynamic h + x record)
    const unsigned short* hrp = &hsp2[n16 * HSK];
    const unsigned short* xrp = &xsp[(n16 & 7) * XS + (n16 >> 3) * 8];

    __syncthreads();

    // x prefetch for s=0 (xsp stable after init barrier)
    bf16x8 xv = *(const bf16x8*)&xrp[0];

    for (int s = 0; s < TT; ++s) {
        // ---- B-frags: h chunks (all lanes), x chunk (q0 rows 64-71) ----
        const bf16x8 B0 = *(const bf16x8*)&hrp[q * 8];
        const bf16x8 B1 = *(const bf16x8*)&hrp[32 + q * 8];
        const bf16x8 zf = {0, 0, 0, 0, 0, 0, 0, 0};
        const bf16x8 B2 = (q == 0) ? xv : zf;

        // ---- MFMAs: per tile two independent 3-chains (Ah | Al), sum ----
        f32x4 acc[3];
        #pragma unroll
        for (int t = 0; t < 3; ++t) {
            if (t >= NTILE) continue;
            f32x4 aH = {0.0f, 0.0f, 0.0f, 0.0f};
            f32x4 aL = {0.0f, 0.0f, 0.0f, 0.0f};
            aH = __builtin_amdgcn_mfma_f32_16x16x32_bf16(Ah[t][0], B0, aH, 0, 0, 0);
            aL = __builtin_amdgcn_mfma_f32_16x16x32_bf16(Al[t][0], B0, aL, 0, 0, 0);
            aH = __builtin_amdgcn_mfma_f32_16x16x32_bf16(Ah[t][1], B1, aH, 0, 0, 0);
            aL = __builtin_amdgcn_mfma_f32_16x16x32_bf16(Al[t][1], B1, aL, 0, 0, 0);
            aH = __builtin_amdgcn_mfma_f32_16x16x32_bf16(Ah[t][2], B2, aH, 0, 0, 0);
            aL = __builtin_amdgcn_mfma_f32_16x16x32_bf16(Al[t][2], B2, aL, 0, 0, 0);
            acc[t] = aH + aL;
        }

        // ---- write z: lane (n16=col, q) holds hcols mt*16+q*4..+3 ----
        #pragma unroll
        for (int t = 0; t < 2; ++t) {
            const int gt = 2 * wave + t;
            const int g  = gt >> 2, mt = gt & 3;
            *(f32x4*)&zt[(g * 16 + n16) * ZC + mt * 16 + q * 4] = acc[t];
        }
        if (wave == 7) {   // fre: fold parts (col b + col b+8) via shfl, write fb[b][f]
            f32x4 af;
            #pragma unroll
            for (int r = 0; r < 4; ++r)
                af[r] = acc[2][r] + __shfl_xor(acc[2][r], 8, 64);
            if (n16 < 8) {
                #pragma unroll
                for (int r = 0; r < 4; ++r) {
                    const int f = q * 4 + r;
                    if (f < FF) fb[n16 * 12 + f] = af[r];
                }
            }
        }

        // x prefetch for s+1 (pad row at s=59: in-bounds, unused)
        xv = *(const bf16x8*)&xrp[(s + 1) * 16];

        __syncthreads();

        // ---- P: batch pb, col pc; z = hi-col + lo-col (full product) ----
        // read zc first (longest dependent chain: tanh)
        const float zcH = zt[(2 * 16 + pb) * ZC + pc], zcL = zt[(2 * 16 + pb + 8) * ZC + pc];
        const float ziH = zt[(0 * 16 + pb) * ZC + pc], ziL = zt[(0 * 16 + pb + 8) * ZC + pc];
        const float zsH = zt[(1 * 16 + pb) * ZC + pc], zsL = zt[(1 * 16 + pb + 8) * ZC + pc];
        const float zoH = zt[(3 * 16 + pb) * ZC + pc], zoL = zt[(3 * 16 + pb + 8) * ZC + pc];

        const float4 fb0 = *(const float4*)&fb[pb * 12];
        const float4 fb1 = *(const float4*)&fb[pb * 12 + 4];
        const float2 fb2 = *(const float2*)&fb[pb * 12 + 8];
        float fr[FF];
        fr[0] = hsig_f(fb0.x); fr[1] = hsig_f(fb0.y);
        fr[2] = hsig_f(fb0.z); fr[3] = hsig_f(fb0.w);
        fr[4] = hsig_f(fb1.x); fr[5] = hsig_f(fb1.y);
        fr[6] = hsig_f(fb1.z); fr[7] = hsig_f(fb1.w);
        fr[8] = hsig_f(fb2.x); fr[9] = hsig_f(fb2.y);

        const float cvt = tanh_f(zcH + zcL);
        const float iv  = hsig_f(ziH + ziL);
        const float stv = hsig_f(zsH + zsL);
        const float ov  = hsig_f(zoH + zoL);
        const float cv  = iv * cvt;

        float aacc0 = bav, aacc1 = 0.0f;
        #pragma unroll
        for (int f = 0; f < FF; ++f) {
            const float fc = stv * fr[f];
            // T' = fc * (R_f * T) + cv,  R_f = cos - i sin
            const float tre = fmaf(SRT[f], Tim[f],  CRT[f] * Tre[f]);
            const float tim = fmaf(CRT[f], Tim[f], -SRT[f] * Tre[f]);
            Tre[f] = fmaf(fc, tre, cv);
            Tim[f] = fc * tim;
            const float A = fmaf(Tim[f], Tim[f], Tre[f] * Tre[f]);
            if (f & 1) aacc1 = fmaf(A, uav[f], aacc1);
            else       aacc0 = fmaf(A, uav[f], aacc0);
        }
        hv = ov * tanh_f(aacc0 + aacc1);

        // split h -> bf16 hi/lo rows (the ONLY conversion point)
        {
            const unsigned short hb = f2bf(hv);
            hsp2[pb * HSK + pc]       = hb;
            hsp2[(8 + pb) * HSK + pc] = f2bf(hv - bf2f(hb));
        }
        __syncthreads();
    }

    // ---- output: out[b] = sum_col h*W_p + b_p ----
    // lane bits: pb = lane&7, pc-octet bits = lane>>3 -> fold lanes 8,16,32
    float val = hv * wpv;
    val += __shfl_xor(val, 8, 64);
    val += __shfl_xor(val, 16, 64);
    val += __shfl_xor(val, 32, 64);
    if (lane < 8) red[wave][lane] = val;
    __syncthreads();
    if (tid < NB) {
        float acc = bpv;
        #pragma unroll
        for (int w = 0; w < 8; ++w) acc += red[w][tid];
        out[b0 + tid] = acc;
    }
}

extern "C" void kernel_launch(void* const* d_in, const int* in_sizes, int n_in,
                              void* d_out, int out_size, void* d_ws, size_t ws_size,
                              hipStream_t stream) {
    (void)in_sizes; (void)n_in; (void)d_ws; (void)ws_size; (void)out_size;
    const float* x     = (const float*)d_in[0];
    const float* W_i   = (const float*)d_in[1];
    const float* U_i   = (const float*)d_in[2];
    const float* b_i   = (const float*)d_in[3];
    const float* W_ste = (const float*)d_in[4];
    const float* U_ste = (const float*)d_in[5];
    const float* b_ste = (const float*)d_in[6];
    const float* W_fre = (const float*)d_in[7];
    const float* U_fre = (const float*)d_in[8];
    const float* b_fre = (const float*)d_in[9];
    const float* W_c   = (const float*)d_in[10];
    const float* U_c   = (const float*)d_in[11];
    const float* b_c   = (const float*)d_in[12];
    const float* W_o   = (const float*)d_in[13];
    const float* U_o   = (const float*)d_in[14];
    const float* b_o   = (const float*)d_in[15];
    const float* U_a   = (const float*)d_in[16];
    const float* b_a   = (const float*)d_in[17];
    const float* W_p   = (const float*)d_in[18];
    const float* b_p   = (const float*)d_in[19];

    sfm_kernel<<<BB / NB, 512, 0, stream>>>(
        x, W_i, U_i, b_i, W_ste, U_ste, b_ste, W_fre, U_fre, b_fre,
        W_c, U_c, b_c, W_o, U_o, b_o, U_a, b_a, W_p, b_p, (float*)d_out);
}